// Round 1
// baseline (98.106 us; speedup 1.0000x reference)
//
#include <hip/hip_runtime.h>

#define D_FEAT 128

// Kernel A: one 64-lane wave per edge.
// Each lane loads float2 from src row and dst row (512B coalesced per row),
// computes partial L1, butterfly-reduces across the wave, lane 0 writes
// e_val[e] = exp(-0.01*L1) and atomicMax's it into seg_max[dst] via the
// positive-float-as-int trick (e_val in (0,1], seg_max zero-initialized).
__global__ void edge_eval_kernel(const float* __restrict__ feats,
                                 const int* __restrict__ src,
                                 const int* __restrict__ dst,
                                 float* __restrict__ e_val,
                                 float* __restrict__ seg_max,
                                 int E) {
    int gtid = blockIdx.x * blockDim.x + threadIdx.x;
    int edge = gtid >> 6;
    int lane = threadIdx.x & 63;
    if (edge >= E) return;

    int s = src[edge];
    int d = dst[edge];

    const float2* fa = (const float2*)(feats + (size_t)s * D_FEAT);
    const float2* fb = (const float2*)(feats + (size_t)d * D_FEAT);
    float2 a = fa[lane];
    float2 b = fb[lane];
    float sum = fabsf(a.x - b.x) + fabsf(a.y - b.y);

    // wave-64 butterfly reduction
    #pragma unroll
    for (int off = 32; off >= 1; off >>= 1)
        sum += __shfl_xor(sum, off, 64);

    if (lane == 0) {
        float ev = expf(-0.01f * sum);
        e_val[edge] = ev;
        // positive floats compare correctly as ints
        atomicMax((int*)(seg_max + d), __float_as_int(ev));
    }
}

// Kernel B: thread per edge. ex = exp(e_val - seg_max[dst]); store into out
// (fully overwritten each call -> deterministic), accumulate seg_sum.
__global__ void edge_exp_kernel(const float* __restrict__ e_val,
                                const int* __restrict__ dst,
                                const float* __restrict__ seg_max,
                                float* __restrict__ seg_sum,
                                float* __restrict__ out,
                                int E) {
    int e = blockIdx.x * blockDim.x + threadIdx.x;
    if (e >= E) return;
    int d = dst[e];
    float ex = expf(e_val[e] - seg_max[d]);
    out[e] = ex;
    atomicAdd(seg_sum + d, ex);
}

// Kernel C: thread per edge. out /= seg_sum[dst].
__global__ void edge_div_kernel(const int* __restrict__ dst,
                                const float* __restrict__ seg_sum,
                                float* __restrict__ out,
                                int E) {
    int e = blockIdx.x * blockDim.x + threadIdx.x;
    if (e >= E) return;
    out[e] = out[e] / seg_sum[dst[e]];
}

extern "C" void kernel_launch(void* const* d_in, const int* in_sizes, int n_in,
                              void* d_out, int out_size, void* d_ws, size_t ws_size,
                              hipStream_t stream) {
    const float* feats = (const float*)d_in[0];
    const int*   eidx  = (const int*)d_in[1];

    const int E = in_sizes[1] / 2;          // 320000
    const int N = in_sizes[0] / D_FEAT;     // 10000

    const int* src = eidx;       // edge_index row 0
    const int* dst = eidx + E;   // edge_index row 1

    float* seg_max = (float*)d_ws;          // [N]
    float* seg_sum = seg_max + N;           // [N]
    float* e_val   = seg_sum + N;           // [E]
    float* out     = (float*)d_out;         // [E]

    // zero seg_max (acts as -inf for positive e_val) and seg_sum
    hipMemsetAsync(d_ws, 0, (size_t)(2 * N) * sizeof(float), stream);

    // Kernel A: 1 wave/edge, 4 waves/block
    {
        dim3 blk(256);
        dim3 grd((E + 3) / 4);
        edge_eval_kernel<<<grd, blk, 0, stream>>>(feats, src, dst, e_val, seg_max, E);
    }
    // Kernel B + C: 1 thread/edge
    {
        dim3 blk(256);
        dim3 grd((E + 255) / 256);
        edge_exp_kernel<<<grd, blk, 0, stream>>>(e_val, dst, seg_max, seg_sum, out, E);
        edge_div_kernel<<<grd, blk, 0, stream>>>(dst, seg_sum, out, E);
    }
}

// Round 2
// 41.831 us; speedup vs baseline: 2.3453x; 2.3453x over previous
//
#include <hip/hip_runtime.h>

#define D_FEAT 128

// Kernel A: 16 lanes per edge (4 edges per wave64).
// Each lane loads 2x float4 from the src row and dst row (512B coalesced per
// row), computes partial L1, reduces across the 16-lane group, and sub-lane 0
// computes p = exp(exp(-0.01*L1)).
// Note: the reference's seg_max subtraction is algebraically a no-op for the
// final ratio (softmax shift invariance), and e in (0,1] makes exp(e) <= 2.72
// -> no overflow, so the max pass is dropped entirely.
__global__ void edge_eval_kernel(const float* __restrict__ feats,
                                 const int* __restrict__ src,
                                 const int* __restrict__ dst,
                                 float* __restrict__ seg_sum,
                                 float* __restrict__ out,
                                 int E) {
    int gtid = blockIdx.x * blockDim.x + threadIdx.x;
    int edge = gtid >> 4;
    int sl   = threadIdx.x & 15;   // sub-lane within the 16-lane group
    if (edge >= E) return;

    int s = src[edge];
    int d = dst[edge];

    const float4* fa = (const float4*)(feats + (size_t)s * D_FEAT);
    const float4* fb = (const float4*)(feats + (size_t)d * D_FEAT);
    // row = 128 floats = 32 float4; 16 lanes x 2 loads cover it
    float4 a0 = fa[sl];
    float4 a1 = fa[sl + 16];
    float4 b0 = fb[sl];
    float4 b1 = fb[sl + 16];

    float sum = fabsf(a0.x - b0.x) + fabsf(a0.y - b0.y)
              + fabsf(a0.z - b0.z) + fabsf(a0.w - b0.w)
              + fabsf(a1.x - b1.x) + fabsf(a1.y - b1.y)
              + fabsf(a1.z - b1.z) + fabsf(a1.w - b1.w);

    // reduce across the 16-lane group (stays within the wave)
    #pragma unroll
    for (int off = 8; off >= 1; off >>= 1)
        sum += __shfl_xor(sum, off, 64);

    if (sl == 0) {
        float p = expf(expf(-0.01f * sum));
        out[edge] = p;
        atomicAdd(seg_sum + d, p);
    }
}

// Kernel B: out[e] /= seg_sum[dst[e]], 4 edges per thread (float4/int4).
__global__ void edge_div_kernel(const int* __restrict__ dst,
                                const float* __restrict__ seg_sum,
                                float* __restrict__ out,
                                int E4) {
    int i = blockIdx.x * blockDim.x + threadIdx.x;
    if (i >= E4) return;
    float4 p = ((const float4*)out)[i];
    int4   d = ((const int4*)dst)[i];
    p.x /= seg_sum[d.x];
    p.y /= seg_sum[d.y];
    p.z /= seg_sum[d.z];
    p.w /= seg_sum[d.w];
    ((float4*)out)[i] = p;
}

// scalar tail (E % 4 != 0) — not hit for E=320000, kept for generality
__global__ void edge_div_tail_kernel(const int* __restrict__ dst,
                                     const float* __restrict__ seg_sum,
                                     float* __restrict__ out,
                                     int start, int E) {
    int e = start + blockIdx.x * blockDim.x + threadIdx.x;
    if (e >= E) return;
    out[e] = out[e] / seg_sum[dst[e]];
}

extern "C" void kernel_launch(void* const* d_in, const int* in_sizes, int n_in,
                              void* d_out, int out_size, void* d_ws, size_t ws_size,
                              hipStream_t stream) {
    const float* feats = (const float*)d_in[0];
    const int*   eidx  = (const int*)d_in[1];

    const int E = in_sizes[1] / 2;          // 320000
    const int N = in_sizes[0] / D_FEAT;     // 10000

    const int* src = eidx;       // edge_index row 0
    const int* dst = eidx + E;   // edge_index row 1

    float* seg_sum = (float*)d_ws;          // [N]
    float* out     = (float*)d_out;         // [E]

    hipMemsetAsync(seg_sum, 0, (size_t)N * sizeof(float), stream);

    // Kernel A: 16 lanes/edge, 256 threads/block -> 16 edges/block
    {
        dim3 blk(256);
        dim3 grd((E + 15) / 16);
        edge_eval_kernel<<<grd, blk, 0, stream>>>(feats, src, dst, seg_sum, out, E);
    }
    // Divide pass: 4 edges/thread
    {
        int E4 = E >> 2;
        if (E4 > 0) {
            dim3 blk(256);
            dim3 grd((E4 + 255) / 256);
            edge_div_kernel<<<grd, blk, 0, stream>>>(dst, seg_sum, out, E4);
        }
        if (E & 3) {
            int start = E4 << 2;
            dim3 blk(64);
            dim3 grd(1);
            edge_div_tail_kernel<<<grd, blk, 0, stream>>>(dst, seg_sum, out, start, E);
        }
    }
}